// Round 11
// baseline (133.784 us; speedup 1.0000x reference)
//
#include <hip/hip_runtime.h>
#include <type_traits>

#define B_ 2
#define S_ 2048
#define D_ 1024
#define H_ 16
#define HD_ 64
#define M_ (B_*S_)

typedef __attribute__((ext_vector_type(8))) short bf16x8;
typedef __attribute__((ext_vector_type(4))) short s16x4;
typedef __attribute__((ext_vector_type(4))) float f32x4;
typedef __attribute__((ext_vector_type(4))) unsigned int u32x4;

static __device__ __forceinline__ unsigned short f2bf(float f) {
  unsigned int u = __builtin_bit_cast(unsigned int, f);
  u += 0x7FFFu + ((u >> 16) & 1u);   // RNE
  return (unsigned short)(u >> 16);
}

static __device__ __forceinline__ unsigned int cvt_pk_bf16(float a, float b) {
  unsigned int r;
  asm("v_cvt_pk_bf16_f32 %0, %1, %2" : "=v"(r) : "v"(a), "v"(b));
  return r;   // lo = bf16(a), hi = bf16(b)
}

static __device__ __forceinline__ void gload_lds16(const void* g, void* l) {
  __builtin_amdgcn_global_load_lds(
      (const __attribute__((address_space(1))) unsigned int*)g,
      (__attribute__((address_space(3))) unsigned int*)l, 16, 0, 0);
}

// ---------- K0a: x fp32 -> bf16 ----------
__global__ __launch_bounds__(256) void xcvt_kernel(const float* __restrict__ x,
                                                   unsigned short* __restrict__ xb) {
  size_t i = ((size_t)blockIdx.x * 256 + threadIdx.x) * 8;
  float4 a = ((const float4*)(x + i))[0];
  float4 b = ((const float4*)(x + i))[1];
  bf16x8 w;
  w[0]=(short)f2bf(a.x); w[1]=(short)f2bf(a.y); w[2]=(short)f2bf(a.z); w[3]=(short)f2bf(a.w);
  w[4]=(short)f2bf(b.x); w[5]=(short)f2bf(b.y); w[6]=(short)f2bf(b.z); w[7]=(short)f2bf(b.w);
  *(bf16x8*)(xb + i) = w;
}

// ---------- K0b: transpose + convert weights: Wt[z][n][k] = bf16(W_z[k][n]) ----------
__global__ void wtrans_kernel(const float* __restrict__ Wq, const float* __restrict__ Wk,
                              const float* __restrict__ Wv, const float* __restrict__ Wo,
                              unsigned short* __restrict__ wt) {
  __shared__ float tile[32][33];
  const float* W = blockIdx.z==0 ? Wq : blockIdx.z==1 ? Wk : blockIdx.z==2 ? Wv : Wo;
  unsigned short* out = wt + (size_t)blockIdx.z * D_ * D_;
  int n0 = blockIdx.x*32, k0 = blockIdx.y*32;
  int tx = threadIdx.x, ty = threadIdx.y;   // 32 x 8
  #pragma unroll
  for (int i=0;i<4;i++) tile[ty+i*8][tx] = W[(size_t)(k0+ty+i*8)*D_ + n0+tx];
  __syncthreads();
  #pragma unroll
  for (int i=0;i<4;i++) out[(size_t)(n0+ty+i*8)*D_ + (k0+tx)] = f2bf(tile[tx][ty+i*8]);
}

// ---------- shared GEMM tile body (m97 structure, BK=64, XOR-swizzled LDS) ----------
#define GEMM_K_LOOP(Abase, Bbase)                                                     \
  for (int ks = 0; ks < 16; ++ks) {                                                   \
    const int k0 = ks * 64;                                                           \
    __syncthreads();                                                                  \
    _Pragma("unroll")                                                                 \
    for (int p = 0; p < 4; ++p) {                                                     \
      int c = p*256 + t;                                                              \
      int row = c >> 3, sl = (c & 7) ^ (row & 7);                                     \
      gload_lds16(Abase + (size_t)row*D_ + k0 + sl*8, &As[(p*256 + wid*64)*8]);       \
    }                                                                                 \
    _Pragma("unroll")                                                                 \
    for (int p = 0; p < 4; ++p) {                                                     \
      int c = p*256 + t;                                                              \
      int row = c >> 3, sl = (c & 7) ^ (row & 7);                                     \
      gload_lds16(Bbase + (size_t)row*D_ + k0 + sl*8, &Bs[(p*256 + wid*64)*8]);       \
    }                                                                                 \
    __syncthreads();                                                                  \
    _Pragma("unroll")                                                                 \
    for (int kk = 0; kk < 2; ++kk) {                                                  \
      bf16x8 af[4], bfr[4];                                                           \
      _Pragma("unroll")                                                               \
      for (int m = 0; m < 4; ++m) {                                                   \
        int row = wr + m*16 + l15;                                                    \
        af[m] = *(const bf16x8*)((const char*)As + row*128 + (((kk*4+lg)^(row&7))<<4)); \
      }                                                                               \
      _Pragma("unroll")                                                               \
      for (int n = 0; n < 4; ++n) {                                                   \
        int row = wc + n*16 + l15;                                                    \
        bfr[n] = *(const bf16x8*)((const char*)Bs + row*128 + (((kk*4+lg)^(row&7))<<4)); \
      }                                                                               \
      _Pragma("unroll")                                                               \
      for (int m = 0; m < 4; ++m)                                                     \
        _Pragma("unroll")                                                             \
        for (int n = 0; n < 4; ++n)                                                   \
          acc[m][n] = __builtin_amdgcn_mfma_f32_16x16x32_bf16(af[m], bfr[n], acc[m][n], 0,0,0); \
    }                                                                                 \
  }

// ---------- K1: QKV projection GEMM (bf16 x bf16) ----------
// Q is pre-scaled by log2(e)/8 so attention can use exp2(score) directly.
__global__ __launch_bounds__(256,3) void gemm_qkv_kernel(
    const unsigned short* __restrict__ xb, const unsigned short* __restrict__ wt,
    unsigned short* __restrict__ Qo, unsigned short* __restrict__ Ko,
    unsigned short* __restrict__ Vto) {
  __shared__ __align__(16) unsigned short As[128*64];
  __shared__ __align__(16) unsigned short Bs[128*64];
  const int z = blockIdx.z;
  const int m0 = blockIdx.y*128, n0 = blockIdx.x*128;
  const int t = threadIdx.x, lane = t & 63, wid = t >> 6;
  const int wr = (wid>>1)*64, wc = (wid&1)*64;
  const int l15 = lane & 15, lg = lane >> 4;
  const unsigned short* Ab = xb + (size_t)m0 * D_;
  const unsigned short* Bb = wt + (size_t)z * D_ * D_ + (size_t)n0 * D_;

  f32x4 acc[4][4];
  #pragma unroll
  for (int m=0;m<4;m++)
    #pragma unroll
    for (int n=0;n<4;n++) acc[m][n] = f32x4{0.f,0.f,0.f,0.f};

  GEMM_K_LOOP(Ab, Bb)

  const float qscale = 0.18033688011112042f;  // log2(e)/8
  #pragma unroll
  for (int m=0;m<4;m++) {
    #pragma unroll
    for (int n=0;n<4;n++) {
      #pragma unroll
      for (int r=0;r<4;r++) {
        int gm = m0 + wr + m*16 + lg*4 + r;
        int gn = n0 + wc + n*16 + l15;
        int b = gm >> 11, s = gm & (S_-1);
        int h = gn >> 6,  d = gn & 63;
        float av = acc[m][n][r];
        if (z==0) av *= qscale;
        unsigned short val = f2bf(av);
        if (z==0)      Qo[(((size_t)(b*H_+h))*S_ + s)*HD_ + d] = val;
        else if (z==1) Ko[(((size_t)(b*H_+h))*S_ + s)*HD_ + d] = val;
        else           Vto[(((size_t)(b*H_+h))*HD_ + d)*S_ + s] = val;
      }
    }
  }
}

// ---------- K2: causal flash attention v9 (balanced tile pairs, shared K/V) ----------
// Block = q-tile PAIR (pr, 31-pr): per-block work = (pr+1)+(32-pr) = 33 chunk-units
// for ALL 512 blocks (perfect causal balance, no tail). One chunk loop over the
// longer tile's range; K/V staged once per pair and fragments shared by both tiles.
// Core = v8: swapped QK^T 16x16x32, in-register P (C-layout == 16x16x16 A-layout),
// PV via 16x16x16, no max tracking (fixed m=0 safe), Q pre-scaled by log2(e)/8.
__global__ __launch_bounds__(256,4) void attn_kernel(
    const unsigned short* __restrict__ Q, const unsigned short* __restrict__ K,
    const unsigned short* __restrict__ Vt, unsigned short* __restrict__ ctx) {
  __shared__ __align__(16) unsigned short KT[2][64*64];
  __shared__ __align__(16) unsigned short VT[2][64*64];
  const int t = threadIdx.x, lane = t & 63, wid = t >> 6;
  const int bh = blockIdx.x & 31;
  const int pr = (int)(blockIdx.x >> 5);        // 0..15
  const int b = bh >> 4, h = bh & 15;
  const int qA0 = pr*64 + wid*16;               // tile A rows (light)
  const int qB0 = (31-pr)*64 + wid*16;          // tile B rows (heavy)
  const int nA = pr + 1, nB = 32 - pr;          // chunk counts; loop runs nB
  const unsigned short* Qp = Q  + (size_t)bh * S_ * HD_;
  const unsigned short* Kp = K  + (size_t)bh * S_ * HD_;
  const unsigned short* Vp = Vt + (size_t)bh * HD_ * S_;
  const int l15 = lane & 15, lg = lane >> 4;
  const int rsub = lane >> 3, slot = lane & 7;
  const int sslot = slot ^ rsub;                // source pre-swizzle (row&7 == rsub)

  bf16x8 qfA0 = *(const bf16x8*)(Qp + (size_t)(qA0 + l15)*HD_ + lg*8);
  bf16x8 qfA1 = *(const bf16x8*)(Qp + (size_t)(qA0 + l15)*HD_ + 32 + lg*8);
  bf16x8 qfB0 = *(const bf16x8*)(Qp + (size_t)(qB0 + l15)*HD_ + lg*8);
  bf16x8 qfB1 = *(const bf16x8*)(Qp + (size_t)(qB0 + l15)*HD_ + 32 + lg*8);

  f32x4 oA[4], oB[4];
  #pragma unroll
  for (int dt=0;dt<4;dt++) { oA[dt]=f32x4{0.f,0.f,0.f,0.f}; oB[dt]=f32x4{0.f,0.f,0.f,0.f}; }
  float lsA = 0.f, lsB = 0.f;   // per-lane partials, reduced at the end

  auto stage = [&](int ch, int buf) {
    const int kk0 = ch * 64;
    #pragma unroll
    for (int j=0;j<2;j++) {
      int row = 16*wid + 8*j + rsub;
      gload_lds16(Kp + (size_t)(kk0 + row)*HD_ + sslot*8, &KT[buf][(16*wid + 8*j)*64]);
      gload_lds16(Vp + (size_t)row*S_ + kk0 + sslot*8,    &VT[buf][(16*wid + 8*j)*64]);
    }
  };

  auto chunk_body = [&](int ch, int cur, auto doA_c) {
    constexpr bool DOA = decltype(doA_c)::value;
    const int kk0 = ch * 64;
    const char* Kt = (const char*)&KT[cur][0];
    const char* Vv = (const char*)&VT[cur][0];

    // QK^T swapped: st*[kt]: k = kk0+kt*16+lg*4+r, q = q*0+l15 (K-frags shared)
    f32x4 stA[4], stB[4];
    __builtin_amdgcn_s_setprio(1);
    #pragma unroll
    for (int kt=0; kt<4; ++kt) {
      int row = kt*16 + l15;
      int sw = (row & 7) << 4;
      bf16x8 kf0 = *(const bf16x8*)(Kt + row*128 + ((lg*16)      ^ sw));
      bf16x8 kf1 = *(const bf16x8*)(Kt + row*128 + ((64 + lg*16) ^ sw));
      f32x4 zB = f32x4{0.f,0.f,0.f,0.f};
      zB = __builtin_amdgcn_mfma_f32_16x16x32_bf16(kf0, qfB0, zB, 0,0,0);
      zB = __builtin_amdgcn_mfma_f32_16x16x32_bf16(kf1, qfB1, zB, 0,0,0);
      stB[kt] = zB;
      if (DOA) {
        f32x4 zA = f32x4{0.f,0.f,0.f,0.f};
        zA = __builtin_amdgcn_mfma_f32_16x16x32_bf16(kf0, qfA0, zA, 0,0,0);
        zA = __builtin_amdgcn_mfma_f32_16x16x32_bf16(kf1, qfA1, zA, 0,0,0);
        stA[kt] = zA;
      }
    }
    __builtin_amdgcn_s_setprio(0);

    if (ch == nB-1) {            // tile B diagonal chunk
      const int q = qB0 + l15;
      #pragma unroll
      for (int kt=0;kt<4;kt++)
        #pragma unroll
        for (int r=0;r<4;r++)
          if (kk0 + kt*16 + lg*4 + r > q) stB[kt][r] = -INFINITY;
    }
    if (DOA && ch == nA-1) {     // tile A diagonal chunk
      const int q = qA0 + l15;
      #pragma unroll
      for (int kt=0;kt<4;kt++)
        #pragma unroll
        for (int r=0;r<4;r++)
          if (kk0 + kt*16 + lg*4 + r > q) stA[kt][r] = -INFINITY;
    }

    // P = exp2(score); per-lane sums; in-lane pack to PV A-frags (identity layout)
    s16x4 paA[4], paB[4];
    #pragma unroll
    for (int kt=0;kt<4;kt++) {
      #pragma unroll
      for (int r=0;r<4;r++) {
        float p = exp2f(stB[kt][r]); stB[kt][r] = p; lsB += p;
        if (DOA) { float pa = exp2f(stA[kt][r]); stA[kt][r] = pa; lsA += pa; }
      }
      uint2 uB; uB.x = cvt_pk_bf16(stB[kt][0], stB[kt][1]);
      uB.y = cvt_pk_bf16(stB[kt][2], stB[kt][3]);
      paB[kt] = __builtin_bit_cast(s16x4, uB);
      if (DOA) {
        uint2 uA; uA.x = cvt_pk_bf16(stA[kt][0], stA[kt][1]);
        uA.y = cvt_pk_bf16(stA[kt][2], stA[kt][3]);
        paA[kt] = __builtin_bit_cast(s16x4, uA);
      }
    }

    // PV via 16x16x16; V-frags shared by both tiles
    __builtin_amdgcn_s_setprio(1);
    #pragma unroll
    for (int dt=0;dt<4;dt++) {
      int row = dt*16 + l15;
      int sw = (row & 7) << 4;
      const char* vrow = Vv + row*128;
      #pragma unroll
      for (int kt=0;kt<4;kt++) {
        s16x4 vb = *(const s16x4*)(vrow + ((kt*32 + lg*8) ^ sw));
        oB[dt] = __builtin_amdgcn_mfma_f32_16x16x16bf16_1k(paB[kt], vb, oB[dt], 0,0,0);
        if (DOA) oA[dt] = __builtin_amdgcn_mfma_f32_16x16x16bf16_1k(paA[kt], vb, oA[dt], 0,0,0);
      }
    }
    __builtin_amdgcn_s_setprio(0);
  };

  stage(0, 0);
  __syncthreads();

  for (int ch=0; ch<nB; ++ch) {
    const int cur = ch & 1;
    if (ch + 1 < nB) stage(ch+1, cur^1);
    if (ch < nA) chunk_body(ch, cur, std::true_type{});
    else         chunk_body(ch, cur, std::false_type{});
    __syncthreads();   // drains vmcnt (next chunk staged) + protects K/V buffers
  }

  // epilogues (lsum: reduce per-lane partials over the 4 lg groups)
  lsA += __shfl_xor(lsA, 16); lsA += __shfl_xor(lsA, 32);
  lsB += __shfl_xor(lsB, 16); lsB += __shfl_xor(lsB, 32);
  float liA = 1.f / lsA, liB = 1.f / lsB;
  #pragma unroll
  for (int r=0;r<4;r++) {
    float lrA = __shfl(liA, lg*4 + r);
    float lrB = __shfl(liB, lg*4 + r);
    size_t rowA = (size_t)(b*S_ + qA0 + lg*4 + r);
    size_t rowB = (size_t)(b*S_ + qB0 + lg*4 + r);
    #pragma unroll
    for (int dt=0;dt<4;dt++) {
      ctx[rowA*D_ + h*HD_ + dt*16 + l15] = f2bf(oA[dt][r] * lrA);
      ctx[rowB*D_ + h*HD_ + dt*16 + l15] = f2bf(oB[dt][r] * lrB);
    }
  }
}

// ---------- K3: output projection GEMM + bias (bf16 -> fp32 out) ----------
__global__ __launch_bounds__(256,3) void gemm_out_kernel(
    const unsigned short* __restrict__ ctx, const unsigned short* __restrict__ WtO,
    const float* __restrict__ bo, float* __restrict__ out) {
  __shared__ __align__(16) unsigned short As[128*64];
  __shared__ __align__(16) unsigned short Bs[128*64];
  const int m0 = blockIdx.y*128, n0 = blockIdx.x*128;
  const int t = threadIdx.x, lane = t & 63, wid = t >> 6;
  const int wr = (wid>>1)*64, wc = (wid&1)*64;
  const int l15 = lane & 15, lg = lane >> 4;
  const unsigned short* Ab = ctx + (size_t)m0 * D_;
  const unsigned short* Bb = WtO + (size_t)n0 * D_;

  f32x4 acc[4][4];
  #pragma unroll
  for (int m=0;m<4;m++)
    #pragma unroll
    for (int n=0;n<4;n++) acc[m][n] = f32x4{0.f,0.f,0.f,0.f};

  GEMM_K_LOOP(Ab, Bb)

  #pragma unroll
  for (int n=0;n<4;n++) {
    float bias = bo[n0 + wc + n*16 + l15];
    #pragma unroll
    for (int m=0;m<4;m++)
      #pragma unroll
      for (int r=0;r<4;r++) {
        int gm = m0 + wr + m*16 + lg*4 + r;
        int gn = n0 + wc + n*16 + l15;
        out[(size_t)gm*D_ + gn] = acc[m][n][r] + bias;
      }
  }
}

extern "C" void kernel_launch(void* const* d_in, const int* in_sizes, int n_in,
                              void* d_out, int out_size, void* d_ws, size_t ws_size,
                              hipStream_t stream) {
  (void)in_sizes; (void)n_in; (void)out_size; (void)ws_size;
  const float* x  = (const float*)d_in[0];
  const float* Wq = (const float*)d_in[1];
  const float* Wk = (const float*)d_in[2];
  const float* Wv = (const float*)d_in[3];
  const float* Wo = (const float*)d_in[4];
  const float* bo = (const float*)d_in[5];
  float* out = (float*)d_out;

  unsigned short* wt  = (unsigned short*)d_ws;            // 4 * D*D bf16 (transposed weights)
  unsigned short* Qb  = wt  + (size_t)4*D_*D_;            // [B,H,S,HD] (pre-scaled by log2e/8)
  unsigned short* Kb  = Qb  + (size_t)M_*D_;              // [B,H,S,HD]
  unsigned short* Vtb = Kb  + (size_t)M_*D_;              // [B,H,HD,S]
  unsigned short* ctb = Vtb + (size_t)M_*D_;              // [B,S,D]
  unsigned short* xbb = ctb + (size_t)M_*D_;              // [M,D] bf16 x

  xcvt_kernel<<<dim3(M_*D_/(256*8)), 256, 0, stream>>>(x, xbb);
  wtrans_kernel<<<dim3(32,32,4), dim3(32,8), 0, stream>>>(Wq, Wk, Wv, Wo, wt);
  gemm_qkv_kernel<<<dim3(8,32,3), 256, 0, stream>>>(xbb, wt, Qb, Kb, Vtb);
  attn_kernel<<<dim3(512), 256, 0, stream>>>(Qb, Kb, Vtb, ctb);
  gemm_out_kernel<<<dim3(8,32), 256, 0, stream>>>(ctb, wt + (size_t)3*D_*D_, bo, out);
}